// Round 1
// baseline (661.919 us; speedup 1.0000x reference)
//
#include <hip/hip_runtime.h>
#include <stdint.h>

#define IN_F 4096
#define OUT_F 4096

typedef __attribute__((ext_vector_type(8))) __bf16 bf16x8;
typedef __attribute__((ext_vector_type(8))) short short8;
typedef __attribute__((ext_vector_type(4))) float f32x4;

struct SelState {
  unsigned int hist[3 * 2048];
  unsigned int prefix;     // accumulates selected bin bits; after round 2 = threshold bit pattern
  unsigned int remaining;  // k remaining within current prefix
  unsigned int count;
  float sum;
  float scale;
};

__device__ __forceinline__ unsigned short f2bf_rne(unsigned int u) {
  // round-to-nearest-even fp32 -> bf16 (inputs are finite, no NaN handling needed)
  return (unsigned short)((u + 0x7FFFu + ((u >> 16) & 1u)) >> 16);
}

__global__ void init_kernel(SelState* st, unsigned int k) {
  int t = threadIdx.x;
  for (int i = t; i < 3 * 2048; i += 256) st->hist[i] = 0;
  if (t == 0) {
    st->prefix = 0;
    st->remaining = k;
    st->count = 0;
    st->sum = 0.0f;
  }
}

__global__ void cast_x_kernel(const float4* __restrict__ x, ushort4* __restrict__ xb, int n4) {
  int i = blockIdx.x * blockDim.x + threadIdx.x;
  int stride = gridDim.x * blockDim.x;
  for (; i < n4; i += stride) {
    float4 v = x[i];
    ushort4 o;
    o.x = f2bf_rne(__float_as_uint(v.x));
    o.y = f2bf_rne(__float_as_uint(v.y));
    o.z = f2bf_rne(__float_as_uint(v.z));
    o.w = f2bf_rne(__float_as_uint(v.w));
    xb[i] = o;
  }
}

// Radix-select histogram. round 0: bits[30:20] (2048 bins); round 1: bits[19:10]
// among prefix matches (1024 bins); round 2: bits[9:0] (1024 bins).
__global__ void hist_kernel(const float4* __restrict__ w, int n4, SelState* st, int round) {
  __shared__ unsigned int lh[2048];
  int nbins = (round == 0) ? 2048 : 1024;
  int t = threadIdx.x;
  for (int i = t; i < nbins; i += 256) lh[i] = 0;
  __syncthreads();
  unsigned int prefix = st->prefix;
  int i = blockIdx.x * blockDim.x + t;
  int stride = gridDim.x * blockDim.x;
  for (; i < n4; i += stride) {
    float4 v = w[i];
#pragma unroll
    for (int c = 0; c < 4; ++c) {
      unsigned int u = __float_as_uint(((const float*)&v)[c]) & 0x7FFFFFFFu;
      if (round == 0) {
        atomicAdd(&lh[u >> 20], 1u);
      } else if (round == 1) {
        if ((u >> 20) == prefix) atomicAdd(&lh[(u >> 10) & 1023u], 1u);
      } else {
        if ((u >> 10) == prefix) atomicAdd(&lh[u & 1023u], 1u);
      }
    }
  }
  __syncthreads();
  unsigned int* gh = st->hist + round * 2048;
  for (int b = t; b < nbins; b += 256) {
    unsigned int c = lh[b];
    if (c) atomicAdd(&gh[b], c);
  }
}

// Single block: find bin containing the remaining-th smallest; update prefix/remaining.
__global__ void scan_kernel(SelState* st, int round) {
  __shared__ unsigned int part[256];
  __shared__ unsigned int sh[2];
  __shared__ unsigned int segbins[8];
  int t = threadIdx.x;
  int nbins = (round == 0) ? 2048 : 1024;
  int per = nbins / 256;
  unsigned int* h = st->hist + round * 2048;
  unsigned int s = 0;
  for (int i = 0; i < per; ++i) s += h[t * per + i];
  part[t] = s;
  __syncthreads();
  if (t == 0) {
    unsigned int rem = st->remaining;
    int seg = 255;
    for (int i = 0; i < 256; ++i) {
      if (part[i] >= rem) { seg = i; break; }
      rem -= part[i];
    }
    sh[0] = (unsigned int)seg;
    sh[1] = rem;
  }
  __syncthreads();
  int seg = (int)sh[0];
  if (t < per) segbins[t] = h[seg * per + t];
  __syncthreads();
  if (t == 0) {
    unsigned int rem = sh[1];
    int b = seg * per + per - 1;
    for (int i = 0; i < per; ++i) {
      unsigned int c = segbins[i];
      if (c >= rem) { b = seg * per + i; break; }
      rem -= c;
    }
    st->remaining = rem;
    int width = (round == 0) ? 11 : 10;
    st->prefix = (st->prefix << width) | (unsigned int)b;
  }
}

// Ternary-quantize weights to bf16 {-1,0,+1}; fused sum(|w|*mask)/count reduction.
__global__ void quant_kernel(const float4* __restrict__ w, ushort4* __restrict__ wt,
                             int n4, SelState* st) {
  unsigned int thr = st->prefix;
  int t = threadIdx.x;
  float lsum = 0.0f;
  unsigned int lcnt = 0;
  int i = blockIdx.x * blockDim.x + t;
  int stride = gridDim.x * blockDim.x;
  for (; i < n4; i += stride) {
    float4 v = w[i];
    ushort4 o;
    unsigned short* op = (unsigned short*)&o;
#pragma unroll
    for (int c = 0; c < 4; ++c) {
      unsigned int u = __float_as_uint(((const float*)&v)[c]);
      unsigned int a = u & 0x7FFFFFFFu;
      bool keep = a > thr;  // strict >, bit-exact vs reference
      op[c] = keep ? (unsigned short)(0x3F80u | ((u >> 16) & 0x8000u)) : (unsigned short)0;
      if (keep) {
        lsum += __uint_as_float(a);
        lcnt++;
      }
    }
    wt[i] = o;
  }
#pragma unroll
  for (int off = 32; off > 0; off >>= 1) {
    lsum += __shfl_down(lsum, off);
    lcnt += __shfl_down(lcnt, off);
  }
  __shared__ float ssum[4];
  __shared__ unsigned int scnt[4];
  int wave = t >> 6, lane = t & 63;
  if (lane == 0) { ssum[wave] = lsum; scnt[wave] = lcnt; }
  __syncthreads();
  if (t == 0) {
    float fs = ssum[0] + ssum[1] + ssum[2] + ssum[3];
    unsigned int fc = scnt[0] + scnt[1] + scnt[2] + scnt[3];
    atomicAdd(&st->sum, fs);
    atomicAdd(&st->count, fc);
  }
}

__global__ void finalize_kernel(SelState* st) {
  unsigned int c = st->count;
  st->scale = st->sum / (float)(c ? c : 1u);
}

__device__ __forceinline__ void async_copy16(const unsigned short* g, unsigned short* l) {
  __builtin_amdgcn_global_load_lds(
      (const __attribute__((address_space(1))) void*)g,
      (__attribute__((address_space(3))) void*)l, 16, 0, 0);
}

// m97-structure GEMM: C[m][n] = scale * sum_k A[m][k]*B[n][k] + bias[n]
// A: M x K bf16 (x), B: N x K bf16 (ternary weights). 128x128 tile, BK=64.
__global__ void gemm_kernel(const unsigned short* __restrict__ A,
                            const unsigned short* __restrict__ B,
                            const float* __restrict__ bias,
                            const SelState* __restrict__ st,
                            float* __restrict__ C, int M, int N, int K) {
  __shared__ __align__(16) unsigned short As[128 * 64];
  __shared__ __align__(16) unsigned short Bs[128 * 64];
  int t = threadIdx.x;
  int wave = t >> 6;
  int lane = t & 63;
  int wm = wave >> 1, wn = wave & 1;
  int l16 = lane & 15, quad = lane >> 4;
  int rowBase = blockIdx.y * 128;
  int colBase = blockIdx.x * 128;
  const unsigned short* Ag = A + (size_t)rowBase * K;
  const unsigned short* Bg = B + (size_t)colBase * K;

  f32x4 acc[4][4];
#pragma unroll
  for (int i = 0; i < 4; ++i)
#pragma unroll
    for (int j = 0; j < 4; ++j) acc[i][j] = {0.0f, 0.0f, 0.0f, 0.0f};

  for (int k0 = 0; k0 < K; k0 += 64) {
#pragma unroll
    for (int i = 0; i < 4; ++i) {
      int c = i * 256 + t;      // chunk id; within a wave: base + lane -> LDS base + lane*16
      int r = c >> 3;           // tile row
      int cc = (c & 7) * 8;     // bf16 col within BK=64
      async_copy16(Ag + (size_t)r * K + k0 + cc, As + c * 8);
      async_copy16(Bg + (size_t)r * K + k0 + cc, Bs + c * 8);
    }
    __syncthreads();
    const short8* As8 = (const short8*)As;
    const short8* Bs8 = (const short8*)Bs;
#pragma unroll
    for (int ks = 0; ks < 2; ++ks) {
      bf16x8 af[4], bfr[4];
#pragma unroll
      for (int i = 0; i < 4; ++i) {
        short8 ar = As8[(wm * 64 + i * 16 + l16) * 8 + ks * 4 + quad];
        short8 br = Bs8[(wn * 64 + i * 16 + l16) * 8 + ks * 4 + quad];
        af[i] = __builtin_bit_cast(bf16x8, ar);
        bfr[i] = __builtin_bit_cast(bf16x8, br);
      }
#pragma unroll
      for (int i = 0; i < 4; ++i)
#pragma unroll
        for (int j = 0; j < 4; ++j)
          acc[i][j] = __builtin_amdgcn_mfma_f32_16x16x32_bf16(af[i], bfr[j], acc[i][j], 0, 0, 0);
    }
    __syncthreads();
  }

  float scale = st->scale;
  float bv[4];
#pragma unroll
  for (int j = 0; j < 4; ++j) bv[j] = bias[colBase + wn * 64 + j * 16 + l16];
#pragma unroll
  for (int i = 0; i < 4; ++i) {
    int row0 = rowBase + wm * 64 + i * 16 + quad * 4;
#pragma unroll
    for (int j = 0; j < 4; ++j) {
      int col = colBase + wn * 64 + j * 16 + l16;
#pragma unroll
      for (int r = 0; r < 4; ++r) {
        C[(size_t)(row0 + r) * N + col] = scale * acc[i][j][r] + bv[j];
      }
    }
  }
}

extern "C" void kernel_launch(void* const* d_in, const int* in_sizes, int n_in,
                              void* d_out, int out_size, void* d_ws, size_t ws_size,
                              hipStream_t stream) {
  const float* x = (const float*)d_in[0];
  const float* w = (const float*)d_in[1];
  const float* bias = (const float*)d_in[2];
  float* out = (float*)d_out;
  const int K = IN_F, N = OUT_F;
  const int n_w = in_sizes[1];            // 4096*4096
  const int n_x = in_sizes[0];            // 4*2048*4096
  const int M = n_x / K;                  // 8192
  const unsigned int k = (unsigned int)(n_w / 2);  // int(n * 0.5), 1-indexed kth

  char* ws = (char*)d_ws;
  SelState* st = (SelState*)ws;
  unsigned short* wt = (unsigned short*)(ws + 65536);                              // 32 MB
  unsigned short* xb = (unsigned short*)(ws + 65536 + (size_t)N * K * 2);          // 64 MB

  hipLaunchKernelGGL(init_kernel, dim3(1), dim3(256), 0, stream, st, k);
  hipLaunchKernelGGL(cast_x_kernel, dim3(4096), dim3(256), 0, stream,
                     (const float4*)x, (ushort4*)xb, n_x / 4);
  for (int r = 0; r < 3; ++r) {
    hipLaunchKernelGGL(hist_kernel, dim3(1024), dim3(256), 0, stream,
                       (const float4*)w, n_w / 4, st, r);
    hipLaunchKernelGGL(scan_kernel, dim3(1), dim3(256), 0, stream, st, r);
  }
  hipLaunchKernelGGL(quant_kernel, dim3(1024), dim3(256), 0, stream,
                     (const float4*)w, (ushort4*)wt, n_w / 4, st);
  hipLaunchKernelGGL(finalize_kernel, dim3(1), dim3(1), 0, stream, st);
  hipLaunchKernelGGL(gemm_kernel, dim3(N / 128, M / 128), dim3(256), 0, stream,
                     xb, wt, bias, st, out, M, N, K);
}